// Round 8
// baseline (106.795 us; speedup 1.0000x reference)
//
#include <hip/hip_runtime.h>
#include <hip/hip_bf16.h>
#include <stdint.h>

#define N_NODES 4096
#define BATCH 2
#define GRID 256

typedef __attribute__((ext_vector_type(8))) short short8v;
typedef __attribute__((ext_vector_type(4))) unsigned short ushort4v;
typedef __attribute__((ext_vector_type(4))) float f32x4;

#define GLL16(gsrc, ldst) \
    __builtin_amdgcn_global_load_lds((const __attribute__((address_space(1))) void*)(gsrc), \
                                     (__attribute__((address_space(3))) void*)(ldst), 16, 0, 0)

static __device__ inline unsigned short f2bf_rn(float x) {
    unsigned u = __float_as_uint(x);
    unsigned r = (u + 0x7FFFu + ((u >> 16) & 1u)) >> 16;
    return (unsigned short)r;
}
static __device__ inline float bf2f(unsigned short b) {
    return __uint_as_float(((unsigned)b) << 16);
}
static __device__ inline float rl(float v, int k) {   // wave-uniform broadcast
    return __uint_as_float(__builtin_amdgcn_readlane(__float_as_uint(v), k));
}

struct KParams {
    const float* emb;
    const float* x;
    const float* Wp;
    const float* bp;
    const float* W1;
    const float* a1s;
    const float* a1d;
    const float* b1;
    const float* W2;
    const float* a2s;
    const float* a2d;
    const float* b2;
    unsigned short* ne_hi;
    unsigned short* ne_lo;
    unsigned long long* mask;
    float* h1;
    float* s1s;
    float* s1d;
    float* h2;
    float* s2s;
    float* s2d;
    float* out;
    unsigned* bar;     // 3 single-use counters, zeroed每 launch by memsetAsync
};

// Software grid barrier: single-use counter (zeroed host-side each launch).
// thread0: release fence -> device-scope add -> acquire spin (invalidates L1)
static __device__ inline void grid_bar(unsigned* ctr) {
    __syncthreads();
    if (threadIdx.x == 0) {
        __threadfence();                                  // release (wb L2)
        atomicAdd(ctr, 1u);                               // device scope
        while (__hip_atomic_load(ctr, __ATOMIC_ACQUIRE,
                                 __HIP_MEMORY_SCOPE_AGENT) < (unsigned)GRID)
            __builtin_amdgcn_s_sleep(2);
    }
    __syncthreads();
}

// ---------------------------------------------------------------------------
// Single kernel, grid = 256 blocks x 256 threads (capacity >= 512 co-resident
// at 64 KiB LDS -> all 256 guaranteed resident; no dispatch-order assumption).
// Phases: A {norm | feat1} -> bar -> B adj (4 tiles/blk) -> bar ->
//         C agg1+mm2+scores2 -> bar -> D agg2.
// ---------------------------------------------------------------------------
__global__ __launch_bounds__(256) void fused_kernel(KParams p) {
    __shared__ unsigned short Ah[128 * 64];
    __shared__ unsigned short Al[128 * 64];
    __shared__ unsigned short Bh[128 * 64];
    __shared__ unsigned short Bl[128 * 64];

    int t = threadIdx.x;
    int bid = blockIdx.x;
    int w = t >> 6, l = t & 63;

    // ================= Phase A: norm (units 0-255) | feat1 (units 256-511) ==
#pragma unroll 1
    for (int u = bid; u < 512; u += GRID) {
        if (u < 256) {
            int row = u * 16 + (t >> 4);
            int l16 = t & 15;
            float4 v = *(const float4*)&p.emb[(size_t)row * 64 + l16 * 4];
            float s = v.x * v.x + v.y * v.y + v.z * v.z + v.w * v.w;
#pragma unroll
            for (int m = 8; m >= 1; m >>= 1) s += __shfl_xor(s, m);
            float inv = 1.f / sqrtf(s);
            float n0 = v.x * inv, n1 = v.y * inv, n2 = v.z * inv, n3 = v.w * inv;
            ushort4v h = {f2bf_rn(n0), f2bf_rn(n1), f2bf_rn(n2), f2bf_rn(n3)};
            ushort4v lo = {f2bf_rn(n0 - bf2f(h.x)), f2bf_rn(n1 - bf2f(h.y)),
                           f2bf_rn(n2 - bf2f(h.z)), f2bf_rn(n3 - bf2f(h.w))};
            *(ushort4v*)&p.ne_hi[(size_t)row * 64 + l16 * 4] = h;
            *(ushort4v*)&p.ne_lo[(size_t)row * 64 + l16 * 4] = lo;
        } else {
            int row0 = (u - 256) * 32 + w * 8;

            float xv[8];
#pragma unroll
            for (int r = 0; r < 8; ++r)
                xv[r] = p.x[(size_t)(row0 + r) * 16 + (l & 15)];

            float h0[8];
            float bpv = p.bp[l];
#pragma unroll
            for (int r = 0; r < 8; ++r) h0[r] = bpv;
#pragma unroll
            for (int k = 0; k < 16; ++k) {
                float wk = p.Wp[k * 64 + l];
#pragma unroll
                for (int r = 0; r < 8; ++r) h0[r] += rl(xv[r], k) * wk;
            }

            float h1v[8] = {0.f, 0.f, 0.f, 0.f, 0.f, 0.f, 0.f, 0.f};
#pragma unroll
            for (int k = 0; k < 64; ++k) {
                float wk = p.W1[k * 64 + l];
#pragma unroll
                for (int r = 0; r < 8; ++r) h1v[r] += rl(h0[r], k) * wk;
            }

            float as_ = p.a1s[l], ad_ = p.a1d[l];
#pragma unroll
            for (int r = 0; r < 8; ++r) {
                p.h1[(size_t)(row0 + r) * 64 + l] = h1v[r];
                float ps = h1v[r] * as_, pd = h1v[r] * ad_;
#pragma unroll
                for (int m = 8; m >= 1; m >>= 1) {
                    ps += __shfl_xor(ps, m);
                    pd += __shfl_xor(pd, m);
                }
                if ((l & 15) == 0) {
                    p.s1s[(size_t)(row0 + r) * 4 + (l >> 4)] = ps;
                    p.s1d[(size_t)(row0 + r) * 4 + (l >> 4)] = pd;
                }
            }
        }
    }
    grid_bar(p.bar + 0);

    // ================= Phase B: adjacency tiles (4 per block) ===============
#pragma unroll 1
    for (int tile = bid; tile < 1024; tile += GRID) {
        int bi = tile >> 5, bj = tile & 31;
        int i0 = bi * 128, j0 = bj * 128;

        int cr = l >> 3;
        int slot = (l & 7) ^ cr;
#pragma unroll
        for (int q = 0; q < 4; ++q) {
            int lr = w * 32 + q * 8;
            size_t ga = (size_t)(i0 + lr + cr) * 64 + slot * 8;
            size_t gb = (size_t)(j0 + lr + cr) * 64 + slot * 8;
            GLL16(p.ne_hi + ga, &Ah[lr * 64]);
            GLL16(p.ne_lo + ga, &Al[lr * 64]);
            GLL16(p.ne_hi + gb, &Bh[lr * 64]);
            GLL16(p.ne_lo + gb, &Bl[lr * 64]);
        }
        __syncthreads();

        int fr = l & 15;
        int s0 = l >> 4;
        int r7 = l & 7;
        short8v aH[2][2], aL[2][2];
#pragma unroll
        for (int rt = 0; rt < 2; ++rt) {
            int base = (w * 32 + rt * 16 + fr) * 64;
            aH[rt][0] = *(const short8v*)&Ah[base + ((s0 ^ r7) << 3)];
            aH[rt][1] = *(const short8v*)&Ah[base + (((s0 + 4) ^ r7) << 3)];
            aL[rt][0] = *(const short8v*)&Al[base + ((s0 ^ r7) << 3)];
            aL[rt][1] = *(const short8v*)&Al[base + (((s0 + 4) ^ r7) << 3)];
        }

        f32x4 acc[2][8];
#pragma unroll
        for (int rt = 0; rt < 2; ++rt)
#pragma unroll
            for (int js = 0; js < 8; ++js) acc[rt][js] = (f32x4){0.f, 0.f, 0.f, 0.f};

#pragma unroll
        for (int js = 0; js < 8; ++js) {
            int bbase = (js * 16 + fr) * 64;
            short8v bH0 = *(const short8v*)&Bh[bbase + ((s0 ^ r7) << 3)];
            short8v bH1 = *(const short8v*)&Bh[bbase + (((s0 + 4) ^ r7) << 3)];
            short8v bL0 = *(const short8v*)&Bl[bbase + ((s0 ^ r7) << 3)];
            short8v bL1 = *(const short8v*)&Bl[bbase + (((s0 + 4) ^ r7) << 3)];
#pragma unroll
            for (int rt = 0; rt < 2; ++rt) {
                f32x4 a = acc[rt][js];
                a = __builtin_amdgcn_mfma_f32_16x16x32_bf16(aH[rt][0], bH0, a, 0, 0, 0);
                a = __builtin_amdgcn_mfma_f32_16x16x32_bf16(aH[rt][1], bH1, a, 0, 0, 0);
                a = __builtin_amdgcn_mfma_f32_16x16x32_bf16(aH[rt][0], bL0, a, 0, 0, 0);
                a = __builtin_amdgcn_mfma_f32_16x16x32_bf16(aH[rt][1], bL1, a, 0, 0, 0);
                a = __builtin_amdgcn_mfma_f32_16x16x32_bf16(aL[rt][0], bH0, a, 0, 0, 0);
                a = __builtin_amdgcn_mfma_f32_16x16x32_bf16(aL[rt][1], bH1, a, 0, 0, 0);
                acc[rt][js] = a;
            }
        }

        int shift = ((l & 15) >> 2) * 16;
        int r = l & 3;
#pragma unroll
        for (int rt = 0; rt < 2; ++rt) {
#pragma unroll
            for (int ws_ = 0; ws_ < 2; ++ws_) {
                unsigned long long w64 = 0;
#pragma unroll
                for (int js2 = 0; js2 < 4; ++js2) {
                    f32x4 a = acc[rt][ws_ * 4 + js2];
                    unsigned long long c0 = __ballot(a[0] > 0.5f);
                    unsigned long long c1 = __ballot(a[1] > 0.5f);
                    unsigned long long c2 = __ballot(a[2] > 0.5f);
                    unsigned long long c3 = __ballot(a[3] > 0.5f);
                    unsigned long long sel = r == 0 ? c0 : r == 1 ? c1 : r == 2 ? c2 : c3;
                    w64 |= ((sel >> shift) & 0xFFFFULL) << (js2 * 16);
                }
                if (l < 16)
                    p.mask[(size_t)(i0 + w * 32 + rt * 16 + l) * 64 + bj * 2 + ws_] = w64;
            }
        }
        __syncthreads();   // LDS reuse guard
    }
    grid_bar(p.bar + 1);

    // ================= Phase C: agg1 (+bias+ReLU) + mm2 + scores2 ==========
    {
        int hh1 = l >> 4;
        int l2 = l & 31;
#pragma unroll 1
        for (int u = bid; u < 512; u += GRID) {
#pragma unroll 1
            for (int rr = 0; rr < 4; ++rr) {
                int row = u * 16 + w * 4 + rr;
                int i = row & (N_NODES - 1);
                int bN = row - i;

                float sd = p.s1d[(size_t)row * 4 + hh1];
                unsigned long long myword = p.mask[(size_t)i * 64 + l];

                float m = -1e30f, denom = 0.f, acc = 0.f;
                unsigned long long nz = __ballot(myword != 0ULL);
                while (nz) {
                    int lw = __ffsll(nz) - 1;
                    nz &= nz - 1;
                    unsigned long long wbits = __shfl(myword, lw);
                    while (wbits) {
                        int bpos = __ffsll(wbits) - 1;
                        wbits &= wbits - 1;
                        int j = (lw << 6) + bpos;
                        float e = sd + p.s1s[(size_t)(bN + j) * 4 + hh1];
                        e = e > 0.f ? e : 0.2f * e;
                        float mn = fmaxf(m, e);
                        float cf = __expf(m - mn);
                        float wg = __expf(e - mn);
                        float hv = p.h1[(size_t)(bN + j) * 64 + l];
                        denom = denom * cf + wg;
                        acc = acc * cf + wg * hv;
                        m = mn;
                    }
                }
                float o = fmaxf(acc / denom + p.b1[l], 0.f);

                float acc2 = 0.f;
#pragma unroll
                for (int k = 0; k < 64; ++k) acc2 += rl(o, k) * p.W2[k * 32 + l2];

                float ps = acc2 * p.a2s[l2], pd = acc2 * p.a2d[l2];
#pragma unroll
                for (int mm = 4; mm >= 1; mm >>= 1) {
                    ps += __shfl_xor(ps, mm);
                    pd += __shfl_xor(pd, mm);
                }
                if (l < 32) {
                    p.h2[(size_t)row * 32 + l] = acc2;
                    if ((l & 7) == 0) {
                        p.s2s[(size_t)row * 4 + (l >> 3)] = ps;
                        p.s2d[(size_t)row * 4 + (l >> 3)] = pd;
                    }
                }
            }
        }
    }
    grid_bar(p.bar + 2);

    // ================= Phase D: agg2 -> out ================================
    {
        int tt = l & 31;
        int hh2 = tt >> 3;
#pragma unroll 1
        for (int u = bid; u < 512; u += GRID) {
#pragma unroll 1
            for (int rr = 0; rr < 4; ++rr) {
                int row = u * 16 + w * 4 + rr;
                int i = row & (N_NODES - 1);
                int bN = row - i;

                float sd = p.s2d[(size_t)row * 4 + hh2];
                unsigned long long myword = p.mask[(size_t)i * 64 + l];

                float m = -1e30f, denom = 0.f, acc = 0.f;
                unsigned long long nz = __ballot(myword != 0ULL);
                while (nz) {
                    int lw = __ffsll(nz) - 1;
                    nz &= nz - 1;
                    unsigned long long wbits = __shfl(myword, lw);
                    while (wbits) {
                        int bpos = __ffsll(wbits) - 1;
                        wbits &= wbits - 1;
                        int j = (lw << 6) + bpos;
                        float e = sd + p.s2s[(size_t)(bN + j) * 4 + hh2];
                        e = e > 0.f ? e : 0.2f * e;
                        float mn = fmaxf(m, e);
                        float cf = __expf(m - mn);
                        float wg = __expf(e - mn);
                        float hv = p.h2[(size_t)(bN + j) * 32 + tt];
                        denom = denom * cf + wg;
                        acc = acc * cf + wg * hv;
                        m = mn;
                    }
                }
                float o = acc / denom + p.b2[tt];
                if (l < 32) p.out[(size_t)row * 32 + tt] = o;
            }
        }
    }
}

// ---------------------------------------------------------------------------
extern "C" void kernel_launch(void* const* d_in, const int* in_sizes, int n_in,
                              void* d_out, int out_size, void* d_ws, size_t ws_size,
                              hipStream_t stream) {
    const int ROWS = BATCH * N_NODES;  // 8192

    char* w = (char*)d_ws;
    unsigned short* ne_hi = (unsigned short*)w;  w += (size_t)N_NODES * 64 * 2;
    unsigned short* ne_lo = (unsigned short*)w;  w += (size_t)N_NODES * 64 * 2;
    unsigned long long* mask = (unsigned long long*)w; w += (size_t)N_NODES * 64 * 8;
    float* h1  = (float*)w;                      w += (size_t)ROWS * 64 * 4;
    float* s1s = (float*)w;                      w += (size_t)ROWS * 4 * 4;
    float* s1d = (float*)w;                      w += (size_t)ROWS * 4 * 4;
    float* h2  = (float*)w;                      w += (size_t)ROWS * 32 * 4;
    float* s2s = (float*)w;                      w += (size_t)ROWS * 4 * 4;
    float* s2d = (float*)w;                      w += (size_t)ROWS * 4 * 4;
    unsigned* bar = (unsigned*)w;                w += 64;

    KParams p;
    p.emb = (const float*)d_in[1];
    p.x   = (const float*)d_in[0];
    p.Wp  = (const float*)d_in[2];
    p.bp  = (const float*)d_in[3];
    p.W1  = (const float*)d_in[4];
    p.a1s = (const float*)d_in[5];
    p.a1d = (const float*)d_in[6];
    p.b1  = (const float*)d_in[7];
    p.W2  = (const float*)d_in[8];
    p.a2s = (const float*)d_in[9];
    p.a2d = (const float*)d_in[10];
    p.b2  = (const float*)d_in[11];
    p.ne_hi = ne_hi;
    p.ne_lo = ne_lo;
    p.mask = mask;
    p.h1 = h1;
    p.s1s = s1s;
    p.s1d = s1d;
    p.h2 = h2;
    p.s2s = s2s;
    p.s2d = s2d;
    p.out = (float*)d_out;
    p.bar = bar;

    // Re-init barrier counters every launch (capture-safe, deterministic).
    hipMemsetAsync(bar, 0, 64, stream);
    fused_kernel<<<dim3(GRID), dim3(256), 0, stream>>>(p);
}